// Round 3
// baseline (1712.838 us; speedup 1.0000x reference)
//
#include <hip/hip_runtime.h>
#include <hip/hip_fp16.h>

// Workspace: 384 MiB (same layout as round 2).
//   A [0,128M):   q_h/l -> k_h/l -> qk (f32)
//   D [128,256M): qT_h/l -> P (64M) + vT (64M)
//   E [256,384M): kk_h/l -> value_h
// d_out scratch (dead before final GEMM): wq_h/l, wk_h/l, wv_h

using half8_t = __attribute__((ext_vector_type(8))) _Float16;
using f32x4   = __attribute__((ext_vector_type(4))) float;

static constexpr int NB = 8;
static constexpr int Sd = 2048;
static constexpr long MAT = (long)Sd * Sd;

__device__ __forceinline__ void gload16(const _Float16* g, _Float16* l) {
  __builtin_amdgcn_global_load_lds(
      (const __attribute__((address_space(1))) void*)g,
      (__attribute__((address_space(3))) void*)l, 16, 0, 0);
}
__device__ __forceinline__ void barrier_() { asm volatile("s_barrier" ::: "memory"); }
#define VMCNT(n) asm volatile("s_waitcnt vmcnt(" #n ")" ::: "memory")

// ---------------------------------------------------------------------------
// presplit: f32 -> fp16 hi (+ residual lo), scaled.
// ---------------------------------------------------------------------------
template<bool SPLIT>
__global__ __launch_bounds__(256) void presplit(const float* __restrict__ in,
    _Float16* __restrict__ h, _Float16* __restrict__ l, long n8, float scl)
{
  long i = (long)blockIdx.x * 256 + threadIdx.x;
  const long stride = (long)gridDim.x * 256;
  for (; i < n8; i += stride) {
    const f32x4* p = (const f32x4*)(in + i * 8);
    f32x4 a = p[0], b = p[1];
    half8_t hh, ll;
#pragma unroll
    for (int j = 0; j < 4; j++) {
      float x = a[j] * scl; _Float16 hv = (_Float16)x;
      hh[j] = hv; if constexpr (SPLIT) ll[j] = (_Float16)(x - (float)hv);
      float y = b[j] * scl; _Float16 hw = (_Float16)y;
      hh[4 + j] = hw; if constexpr (SPLIT) ll[4 + j] = (_Float16)(y - (float)hw);
    }
    *(half8_t*)(h + i * 8) = hh;
    if constexpr (SPLIT) *(half8_t*)(l + i * 8) = ll;
  }
}

// ---------------------------------------------------------------------------
// gemm3 helpers
// ---------------------------------------------------------------------------
__device__ __forceinline__ void stageU(const _Float16* base, _Float16* unit,
                                       int du0, size_t srcoff) {
  gload16(base + srcoff, unit + du0);
  gload16(base + srcoff + (size_t)128 * Sd, unit + du0 + 4096);
}

__device__ __forceinline__ void lda4(const _Float16* unit, int off, int fmhOff,
                                     half8_t (&a)[4]) {
#pragma unroll
  for (int f = 0; f < 4; f++)
    a[f] = *(const half8_t*)((const char*)unit + off + fmhOff + f * 1024);
}

template<int FMH>
__device__ __forceinline__ void mm16(f32x4 (&acc)[8][4], const half8_t (&a)[4],
                                     const half8_t (&b)[4]) {
  __builtin_amdgcn_s_setprio(1);
#pragma unroll
  for (int f = 0; f < 4; f++)
#pragma unroll
    for (int n = 0; n < 4; n++)
      acc[FMH * 4 + f][n] =
          __builtin_amdgcn_mfma_f32_16x16x32_f16(a[f], b[n], acc[FMH * 4 + f][n], 0, 0, 0);
  __builtin_amdgcn_s_setprio(0);
}

// ---------------------------------------------------------------------------
// gemm3 (B^T form): C[i][j] = cscale * sum_k A[i][k]*B[j][k] (+ bias)
// 256x256 tile, BK=64 as 2 K-half units of 256x32, ring of 4 units/operand,
// 4-phase pipelined K-loop with counted vmcnt. 512 threads (8 waves, 2x4).
// NSEG: 1 plain fp16; 3 = K-concat split [Ah|Al|Ah]x[Bh|Bh|Bl] (K=6144).
// BIAS: 0 none, 1 bias[n], 2 bias[m].  OUT: 0 f32, 1 fp16, 2 split fp16 (x16).
// ---------------------------------------------------------------------------
template<int NSEG, int BIAS, int OUT>
__global__ __launch_bounds__(512, 2) void gemm3(
    const _Float16* __restrict__ Ah, const _Float16* __restrict__ Al, long sA,
    const _Float16* __restrict__ Bh, const _Float16* __restrict__ Bl, long sB,
    const float* __restrict__ bias, float cscale,
    void* __restrict__ Cp, void* __restrict__ Clp, long sC)
{
  constexpr int NT = NSEG * 32;
  __shared__ __align__(16) _Float16 LA[4][8192];   // 4 units x 16 KB
  __shared__ __align__(16) _Float16 LB[4][8192];

  const int t = threadIdx.x, w = t >> 6, l = t & 63;

  // XCD swizzle: 512 wgs -> 64 consecutive per XCD (one batch per XCD)
  const int wg = blockIdx.x;
  const int swz = (wg & 7) * 64 + (wg >> 3);
  const int bz = swz >> 6, rem = swz & 63;
  const int by = rem >> 3, bx = rem & 7;

  const _Float16* PAh = Ah + (size_t)bz * sA + (size_t)(by * 256) * Sd;
  const _Float16* PBh = Bh + (size_t)bz * sB + (size_t)(bx * 256) * Sd;
  const _Float16* PAl = (NSEG == 3) ? Al + (size_t)bz * sA + (size_t)(by * 256) * Sd : PAh;
  const _Float16* PBl = (NSEG == 3) ? Bl + (size_t)bz * sB + (size_t)(bx * 256) * Sd : PBh;

  // --- staging geometry (per thread): slot S = i*512 + t holds
  // row 2*(S>>3)+(S&1), k-cols lk*8..+8 with lk = ((S&7)>>1) ^ ((S>>3)&3)
  const int s7 = t & 7;
  const int lkS = (s7 >> 1) ^ ((t >> 3) & 3);
  const size_t srcoff = (size_t)(2 * (t >> 3) + (s7 & 1)) * Sd + lkS * 8;
  const int du0 = w * 512;   // wave-uniform LDS dest base (elems), instr0

  // --- read geometry: frag (ra=wmM+fm*16+lm, k=lkr*8): byte =
  //   (ra>>1)*128 + s'*16,  s' = ((lkr ^ ((ra>>1)&3))<<1) | (ra&1)
  const int wm = (w >> 2) * 128, wn = (w & 3) * 64;
  const int lm = l & 15, lkr = l >> 4;
  const int sprime = ((lkr ^ ((lm >> 1) & 3)) << 1) | (lm & 1);
  const int aoff = (wm >> 1) * 128 + (lm >> 1) * 128 + sprime * 16;
  const int boff = (wn >> 1) * 128 + (lm >> 1) * 128 + sprime * 16;

  f32x4 acc[8][4] = {};
  half8_t a[4], b[4];

  // --- prologue: stage tile 0 fully, order A0,B0,A1,B1
  stageU(PAh + 0,  LA[0], du0, srcoff);
  stageU(PBh + 0,  LB[0], du0, srcoff);
  stageU(PAh + 32, LA[1], du0, srcoff);
  stageU(PBh + 32, LB[1], du0, srcoff);
  VMCNT(4);               // A(0,0),B(0,0) landed
  barrier_();

  for (int kt = 0; kt < NT; ++kt) {
    const int s0 = (2 * kt) & 3, s1 = (2 * kt + 1) & 3;
    const int d0 = (2 * kt + 2) & 3, d1 = (2 * kt + 3) & 3;
    const int kt1 = kt + 1;
    const bool st = (kt1 < NT);
    const _Float16* sa = PAh;
    const _Float16* sb = PBh;
    int ko = 0;
    if (st) {
      if constexpr (NSEG == 3) {
        const int sg = kt1 >> 5; ko = (kt1 & 31) * 64;
        sa = (sg == 1) ? PAl : PAh;   // segs: Ah, Al, Ah
        sb = (sg == 2) ? PBl : PBh;   // segs: Bh, Bh, Bl
      } else {
        ko = kt1 * 64;
      }
    }
    // ---- phase 0: (fm 0-3, kk=0)
    lda4(LA[s0], aoff, 0, a);
    lda4(LB[s0], boff, 0, b);
    if (st) stageU(sa + ko, LA[d0], du0, srcoff);
    barrier_();
    mm16<0>(acc, a, b);
    // ---- phase 1: (fm 4-7, kk=0), B reused from regs
    lda4(LA[s0], aoff, 4096, a);
    if (st) { stageU(sb + ko, LB[d0], du0, srcoff); VMCNT(4); }
    else    { VMCNT(0); }
    barrier_();
    mm16<1>(acc, a, b);
    // ---- phase 2: (fm 0-3, kk=1)
    lda4(LA[s1], aoff, 0, a);
    lda4(LB[s1], boff, 0, b);
    if (st) stageU(sa + ko + 32, LA[d1], du0, srcoff);
    barrier_();
    mm16<0>(acc, a, b);
    // ---- phase 3: (fm 4-7, kk=1)
    lda4(LA[s1], aoff, 4096, a);
    if (st) { stageU(sb + ko + 32, LB[d1], du0, srcoff); VMCNT(4); }
    barrier_();
    mm16<1>(acc, a, b);
  }

  // --- epilogue: C/D layout col = lane&15, row = (lane>>4)*4 + reg
  const int row_base = by * 256 + wm + (lkr << 2);
  const int col_base = bx * 256 + wn + lm;
#pragma unroll
  for (int fm = 0; fm < 8; fm++)
#pragma unroll
    for (int fn = 0; fn < 4; fn++) {
      const int n = col_base + fn * 16;
      float bcol = 0.f;
      if constexpr (BIAS == 1) bcol = bias[n];
#pragma unroll
      for (int r = 0; r < 4; r++) {
        const int m = row_base + fm * 16 + r;
        float v = acc[fm][fn][r] * cscale;
        if constexpr (BIAS == 1) v += bcol;
        if constexpr (BIAS == 2) v += bias[m];
        const size_t ci = (size_t)bz * sC + (size_t)m * Sd + n;
        if constexpr (OUT == 0) ((float*)Cp)[ci] = v;
        else if constexpr (OUT == 1) ((_Float16*)Cp)[ci] = (_Float16)v;
        else {
          float sv = v * 16.0f;
          _Float16 hv = (_Float16)sv;
          ((_Float16*)Cp)[ci]  = hv;
          ((_Float16*)Clp)[ci] = (_Float16)(sv - (float)hv);
        }
      }
    }
}

// ---------------------------------------------------------------------------
// Row softmax: one 256-thread block per row of 2048 f32 -> fp16 probs.
// ---------------------------------------------------------------------------
__global__ __launch_bounds__(256) void softmax_rows(const float* __restrict__ X,
                                                    _Float16* __restrict__ P)
{
  __shared__ float red[4];
  const size_t row = blockIdx.x;
  const float* x = X + row * Sd;
  _Float16* p = P + row * Sd;
  const int t = threadIdx.x;
  float v[8];
  float mx = -1e30f;
#pragma unroll
  for (int i = 0; i < 8; i++) { v[i] = x[t + 256 * i]; mx = fmaxf(mx, v[i]); }
#pragma unroll
  for (int o = 32; o > 0; o >>= 1) mx = fmaxf(mx, __shfl_xor(mx, o, 64));
  if ((t & 63) == 0) red[t >> 6] = mx;
  __syncthreads();
  mx = fmaxf(fmaxf(red[0], red[1]), fmaxf(red[2], red[3]));
  __syncthreads();
  float s = 0.f;
#pragma unroll
  for (int i = 0; i < 8; i++) { v[i] = __expf(v[i] - mx); s += v[i]; }
#pragma unroll
  for (int o = 32; o > 0; o >>= 1) s += __shfl_xor(s, o, 64);
  if ((t & 63) == 0) red[t >> 6] = s;
  __syncthreads();
  s = red[0] + red[1] + red[2] + red[3];
  float inv = 1.f / s;
#pragma unroll
  for (int i = 0; i < 8; i++) p[t + 256 * i] = (_Float16)(v[i] * inv);
}

// ---------------------------------------------------------------------------
extern "C" void kernel_launch(void* const* d_in, const int* in_sizes, int n_in,
                              void* d_out, int out_size, void* d_ws, size_t ws_size,
                              hipStream_t stream)
{
  const float* query = (const float*)d_in[0];
  const float* key_  = (const float*)d_in[1];
  const float* value = (const float*)d_in[2];
  const float* Wq = (const float*)d_in[3];
  const float* bq = (const float*)d_in[4];
  const float* Wk = (const float*)d_in[5];
  const float* bk = (const float*)d_in[6];
  const float* Wv = (const float*)d_in[7];
  const float* bv = (const float*)d_in[8];

  char* ws = (char*)d_ws;
  char* ob = (char*)d_out;
  const size_t M64 = (size_t)NB * MAT * 2;   // 64 MiB

  _Float16* q_h  = (_Float16*)(ws);
  _Float16* q_l  = (_Float16*)(ws + M64);
  _Float16* k_h  = q_h;
  _Float16* k_l  = q_l;
  float*    qk   = (float*)(ws);
  _Float16* qT_h = (_Float16*)(ws + 2 * M64);
  _Float16* qT_l = (_Float16*)(ws + 3 * M64);
  _Float16* P    = qT_h;
  _Float16* vT   = qT_l;
  _Float16* kk_h = (_Float16*)(ws + 4 * M64);
  _Float16* kk_l = (_Float16*)(ws + 5 * M64);
  _Float16* val_h = kk_h;

  _Float16* wq_h = (_Float16*)(ob);
  _Float16* wq_l = (_Float16*)(ob + (MAT * 2));
  _Float16* wk_h = (_Float16*)(ob + 2 * (MAT * 2));
  _Float16* wk_l = (_Float16*)(ob + 3 * (MAT * 2));
  _Float16* wv_h = (_Float16*)(ob + 4 * (MAT * 2));
  float* out = (float*)d_out;

  dim3 blk256(256), blk512(512);
  dim3 gg(512);   // 8 batches x 8x8 tiles of 256
  const long NQ8 = (long)NB * MAT / 8;
  const long NW8 = MAT / 8;

  // 1. presplit query (x16), Wq (x16)
  presplit<true><<<dim3(2048), blk256, 0, stream>>>(query, q_h, q_l, NQ8, 16.f);
  presplit<true><<<dim3(2048), blk256, 0, stream>>>(Wq, wq_h, wq_l, NW8, 16.f);
  // 2. qT[e][s] = sum_d Wq[e][d]*query[s][d] + bq[e] (row bias), split out
  gemm3<3, 2, 2><<<gg, blk512, 0, stream>>>(wq_h, wq_l, 0, q_h, q_l, MAT,
                                            bq, 1.f / 256.f, qT_h, qT_l, MAT);
  // 3. presplit key_ (x16), Wk (x16)
  presplit<true><<<dim3(2048), blk256, 0, stream>>>(key_, k_h, k_l, NQ8, 16.f);
  presplit<true><<<dim3(2048), blk256, 0, stream>>>(Wk, wk_h, wk_l, NW8, 16.f);
  // 4. kk[s'][e] = sum_d key_[s'][d]*Wk[e][d] + bk[e] (col bias), split out
  gemm3<3, 1, 2><<<gg, blk512, 0, stream>>>(k_h, k_l, MAT, wk_h, wk_l, 0,
                                            bk, 1.f / 256.f, kk_h, kk_l, MAT);
  // 5. qk[e][s'] = sum_m qT[e][m]*kk[s'][m]  (f32 out)
  gemm3<3, 0, 0><<<gg, blk512, 0, stream>>>(qT_h, qT_l, MAT, kk_h, kk_l, MAT,
                                            nullptr, 1.f / 256.f, qk, nullptr, MAT);
  // 6. P = row-softmax(qk), fp16
  softmax_rows<<<dim3(NB * Sd), blk256, 0, stream>>>(qk, P);
  // 7. presplit value (x1), Wv (x1)
  presplit<false><<<dim3(2048), blk256, 0, stream>>>(value, val_h, nullptr, NQ8, 1.f);
  presplit<false><<<dim3(2048), blk256, 0, stream>>>(Wv, wv_h, nullptr, NW8, 1.f);
  // 8. vT[d'][s'] = sum_d Wv[d'][d]*value[s'][d] + bv[d'] (row bias), fp16
  gemm3<1, 2, 1><<<gg, blk512, 0, stream>>>(wv_h, nullptr, 0, val_h, nullptr, MAT,
                                            bv, 1.f, vT, nullptr, MAT);
  // 9. out[d'][e] = sum_s' vT[d'][s']*P[e][s']  (f32 -> d_out)
  gemm3<1, 0, 0><<<gg, blk512, 0, stream>>>(vT, nullptr, MAT, P, nullptr, MAT,
                                            nullptr, 1.f, out, nullptr, MAT);
}

// Round 4
// 1686.024 us; speedup vs baseline: 1.0159x; 1.0159x over previous
//
#include <hip/hip_runtime.h>
#include <hip/hip_fp16.h>

// Workspace: 384 MiB (same layout as round 2/3).
//   A [0,128M):   q_h/l -> k_h/l -> qk (f32)
//   D [128,256M): qT_h/l -> P (64M) + vT (64M)
//   E [256,384M): kk_h/l -> value_h
// d_out scratch (dead before final GEMM): wq_h/l, wk_h/l, wv_h

using half8_t = __attribute__((ext_vector_type(8))) _Float16;
using f32x4   = __attribute__((ext_vector_type(4))) float;

static constexpr int NB = 8;
static constexpr int Sd = 2048;
static constexpr long MAT = (long)Sd * Sd;

__device__ __forceinline__ void gload16(const _Float16* g, _Float16* l) {
  __builtin_amdgcn_global_load_lds(
      (const __attribute__((address_space(1))) void*)g,
      (__attribute__((address_space(3))) void*)l, 16, 0, 0);
}
__device__ __forceinline__ void barrier_() { asm volatile("s_barrier" ::: "memory"); }
__device__ __forceinline__ void lgkm0_()   { asm volatile("s_waitcnt lgkmcnt(0)" ::: "memory"); }
#define VMCNT(n) asm volatile("s_waitcnt vmcnt(" #n ")" ::: "memory")

// ---------------------------------------------------------------------------
// presplit: f32 -> fp16 hi (+ residual lo), scaled.
// ---------------------------------------------------------------------------
template<bool SPLIT>
__global__ __launch_bounds__(256) void presplit(const float* __restrict__ in,
    _Float16* __restrict__ h, _Float16* __restrict__ l, long n8, float scl)
{
  long i = (long)blockIdx.x * 256 + threadIdx.x;
  const long stride = (long)gridDim.x * 256;
  for (; i < n8; i += stride) {
    const f32x4* p = (const f32x4*)(in + i * 8);
    f32x4 a = p[0], b = p[1];
    half8_t hh, ll;
#pragma unroll
    for (int j = 0; j < 4; j++) {
      float x = a[j] * scl; _Float16 hv = (_Float16)x;
      hh[j] = hv; if constexpr (SPLIT) ll[j] = (_Float16)(x - (float)hv);
      float y = b[j] * scl; _Float16 hw = (_Float16)y;
      hh[4 + j] = hw; if constexpr (SPLIT) ll[4 + j] = (_Float16)(y - (float)hw);
    }
    *(half8_t*)(h + i * 8) = hh;
    if constexpr (SPLIT) *(half8_t*)(l + i * 8) = ll;
  }
}

// ---------------------------------------------------------------------------
// gemm4 helpers
// ---------------------------------------------------------------------------
__device__ __forceinline__ void stageU(const _Float16* base, _Float16* unit,
                                       int du0, size_t srcoff) {
  gload16(base + srcoff, unit + du0);
  gload16(base + srcoff + (size_t)128 * Sd, unit + du0 + 4096);
}

__device__ __forceinline__ void lda4(const _Float16* unit, int off, int fmhOff,
                                     half8_t (&a)[4]) {
#pragma unroll
  for (int f = 0; f < 4; f++)
    a[f] = *(const half8_t*)((const char*)unit + off + fmhOff + f * 1024);
}

template<int FMH>
__device__ __forceinline__ void mm16(f32x4 (&acc)[8][4], const half8_t (&a)[4],
                                     const half8_t (&b)[4]) {
  __builtin_amdgcn_s_setprio(1);
#pragma unroll
  for (int f = 0; f < 4; f++)
#pragma unroll
    for (int n = 0; n < 4; n++)
      acc[FMH * 4 + f][n] =
          __builtin_amdgcn_mfma_f32_16x16x32_f16(a[f], b[n], acc[FMH * 4 + f][n], 0, 0, 0);
  __builtin_amdgcn_s_setprio(0);
}

// ---------------------------------------------------------------------------
// gemm4 (B^T form): C[i][j] = cscale * sum_k A[i][k]*B[j][k] (+ bias)
// 256x256 tile, BK=64 as 2 K-half units (256x32, 16KB), ring-of-4 per operand,
// m201-discipline 4-phase K-loop: double barrier per phase, lgkmcnt(0) after
// first barrier, setprio around 16-MFMA cluster, staging 2 K-tiles ahead with
// vmcnt(4)@P1 / vmcnt(8)@P3 (deep counted window, never 0 mid-loop).
// 512 threads (8 waves, 2x4). NSEG: 1 plain; 3 = K-concat split (K=6144).
// BIAS: 0 none, 1 bias[n], 2 bias[m].  OUT: 0 f32, 1 fp16, 2 split fp16 (x16).
// ---------------------------------------------------------------------------
template<int NSEG, int BIAS, int OUT>
__global__ __launch_bounds__(512, 2) void gemm4(
    const _Float16* __restrict__ Ah, const _Float16* __restrict__ Al, long sA,
    const _Float16* __restrict__ Bh, const _Float16* __restrict__ Bl, long sB,
    const float* __restrict__ bias, float cscale,
    void* __restrict__ Cp, void* __restrict__ Clp, long sC)
{
  constexpr int NT = NSEG * 32;
  __shared__ __align__(16) _Float16 LA[4][8192];   // ring of 4 units x 16 KB
  __shared__ __align__(16) _Float16 LB[4][8192];

  const int t = threadIdx.x, w = t >> 6, l = t & 63;

  // XCD swizzle: 512 wgs -> 64 consecutive per XCD (one batch per XCD)
  const int wg = blockIdx.x;
  const int swz = (wg & 7) * 64 + (wg >> 3);
  const int bz = swz >> 6, rem = swz & 63;
  const int by = rem >> 3, bx = rem & 7;

  const _Float16* PAh = Ah + (size_t)bz * sA + (size_t)(by * 256) * Sd;
  const _Float16* PBh = Bh + (size_t)bz * sB + (size_t)(bx * 256) * Sd;
  const _Float16* PAl = (NSEG == 3) ? Al + (size_t)bz * sA + (size_t)(by * 256) * Sd : PAh;
  const _Float16* PBl = (NSEG == 3) ? Bl + (size_t)bz * sB + (size_t)(bx * 256) * Sd : PBh;

  // staging geometry: slot S = i*512 + t -> row 2*(S>>3)+(S&1),
  // k-slot lk = ((S&7)>>1) ^ ((S>>3)&3); dest LDS = linear slot*8.
  const int s7 = t & 7;
  const int lkS = (s7 >> 1) ^ ((t >> 3) & 3);
  const size_t srcoff = (size_t)(2 * (t >> 3) + (s7 & 1)) * Sd + lkS * 8;
  const int du0 = w * 512;

  // read geometry (inverse involution; measured conflict-free)
  const int wm = (w >> 2) * 128, wn = (w & 3) * 64;
  const int lm = l & 15, lkr = l >> 4;
  const int sprime = ((lkr ^ ((lm >> 1) & 3)) << 1) | (lm & 1);
  const int aoff = (wm >> 1) * 128 + (lm >> 1) * 128 + sprime * 16;
  const int boff = (wn >> 1) * 128 + (lm >> 1) * 128 + sprime * 16;

  f32x4 acc[8][4] = {};
  half8_t a[4], b[4];

  // segment source select: tile tt -> (srcA, srcB, k-elem offset base)
  auto segA = [&](int tt) -> const _Float16* {
    if constexpr (NSEG == 3) return ((tt >> 5) == 1) ? PAl : PAh;
    return PAh;
  };
  auto segB = [&](int tt) -> const _Float16* {
    if constexpr (NSEG == 3) return ((tt >> 5) == 2) ? PBl : PBh;
    return PBh;
  };
  auto koOf = [&](int tt, int h) -> int {
    if constexpr (NSEG == 3) return (tt & 31) * 64 + h * 32;
    return tt * 64 + h * 32;
  };

  // ---- prologue: T0 fully + T1 h0 (12 loads), force T0-h0 via vmcnt(8)
  stageU(PAh + 0,  LA[0], du0, srcoff);       // A(0,h0) -> slot 0
  stageU(PBh + 0,  LB[0], du0, srcoff);       // B(0,h0)
  stageU(PAh + 32, LA[1], du0, srcoff);       // A(0,h1) -> slot 1
  stageU(PBh + 32, LB[1], du0, srcoff);       // B(0,h1)
  stageU(segA(1) + koOf(1, 0), LA[2], du0, srcoff);  // A(1,h0) -> slot 2
  stageU(segB(1) + koOf(1, 0), LB[2], du0, srcoff);  // B(1,h0)
  VMCNT(8);          // forces A(0,h0), B(0,h0)
  barrier_();

  for (int j = 0; j < NT; ++j) {
    const int a0 = (2 * j) & 3, a1 = (2 * j + 1) & 3;
    const bool s1 = (j + 1 < NT), s2 = (j + 2 < NT);
    const _Float16* sa1 = segA(j + 1); const _Float16* sb1 = segB(j + 1);
    const _Float16* sa2 = segA(j + 2); const _Float16* sb2 = segB(j + 2);
    const int ko1 = koOf(j + 1, 1), ko2 = koOf(j + 2, 0);

    // ---- P0: frags fm0-3, kk0   | stage A(j+1,h1) -> slot a1^2... = (2j+3)&3
    lda4(LA[a0], aoff, 0, a);
    lda4(LB[a0], boff, 0, b);
    if (s1) stageU(sa1 + ko1, LA[(2 * j + 3) & 3], du0, srcoff);
    barrier_(); lgkm0_();
    mm16<0>(acc, a, b);
    barrier_();

    // ---- P1: frags fm4-7, kk0 (b reused) | stage B(j+1,h1); vmcnt(4)
    lda4(LA[a0], aoff, 4096, a);
    if (s1) stageU(sb1 + ko1, LB[(2 * j + 3) & 3], du0, srcoff);
    if (j == NT - 1) { VMCNT(0); } else { VMCNT(4); }
    barrier_(); lgkm0_();
    mm16<1>(acc, a, b);
    barrier_();

    // ---- P2: frags fm0-3, kk1   | stage A(j+2,h0) -> slot a0
    lda4(LA[a1], aoff, 0, a);
    lda4(LB[a1], boff, 0, b);
    if (s2) stageU(sa2 + ko2, LA[a0], du0, srcoff);
    barrier_(); lgkm0_();
    mm16<0>(acc, a, b);
    barrier_();

    // ---- P3: frags fm4-7, kk1   | stage B(j+2,h0) -> slot b0; vmcnt(8)
    lda4(LA[a1], aoff, 4096, a);
    if (s2) stageU(sb2 + ko2, LB[a0], du0, srcoff);
    VMCNT(8);
    barrier_(); lgkm0_();
    mm16<1>(acc, a, b);
    barrier_();
  }

  // ---- epilogue: C/D layout col = lane&15, row = (lane>>4)*4 + reg
  const int row_base = by * 256 + wm + (lkr << 2);
  const int col_base = bx * 256 + wn + lm;
#pragma unroll
  for (int fm = 0; fm < 8; fm++)
#pragma unroll
    for (int fn = 0; fn < 4; fn++) {
      const int n = col_base + fn * 16;
      float bcol = 0.f;
      if constexpr (BIAS == 1) bcol = bias[n];
#pragma unroll
      for (int r = 0; r < 4; r++) {
        const int m = row_base + fm * 16 + r;
        float v = acc[fm][fn][r] * cscale;
        if constexpr (BIAS == 1) v += bcol;
        if constexpr (BIAS == 2) v += bias[m];
        const size_t ci = (size_t)bz * sC + (size_t)m * Sd + n;
        if constexpr (OUT == 0) ((float*)Cp)[ci] = v;
        else if constexpr (OUT == 1) ((_Float16*)Cp)[ci] = (_Float16)v;
        else {
          float sv = v * 16.0f;
          _Float16 hv = (_Float16)sv;
          ((_Float16*)Cp)[ci]  = hv;
          ((_Float16*)Clp)[ci] = (_Float16)(sv - (float)hv);
        }
      }
    }
}

// ---------------------------------------------------------------------------
// Row softmax: one 256-thread block per row of 2048 f32 -> fp16 probs.
// ---------------------------------------------------------------------------
__global__ __launch_bounds__(256) void softmax_rows(const float* __restrict__ X,
                                                    _Float16* __restrict__ P)
{
  __shared__ float red[4];
  const size_t row = blockIdx.x;
  const float* x = X + row * Sd;
  _Float16* p = P + row * Sd;
  const int t = threadIdx.x;
  float v[8];
  float mx = -1e30f;
#pragma unroll
  for (int i = 0; i < 8; i++) { v[i] = x[t + 256 * i]; mx = fmaxf(mx, v[i]); }
#pragma unroll
  for (int o = 32; o > 0; o >>= 1) mx = fmaxf(mx, __shfl_xor(mx, o, 64));
  if ((t & 63) == 0) red[t >> 6] = mx;
  __syncthreads();
  mx = fmaxf(fmaxf(red[0], red[1]), fmaxf(red[2], red[3]));
  __syncthreads();
  float s = 0.f;
#pragma unroll
  for (int i = 0; i < 8; i++) { v[i] = __expf(v[i] - mx); s += v[i]; }
#pragma unroll
  for (int o = 32; o > 0; o >>= 1) s += __shfl_xor(s, o, 64);
  if ((t & 63) == 0) red[t >> 6] = s;
  __syncthreads();
  s = red[0] + red[1] + red[2] + red[3];
  float inv = 1.f / s;
#pragma unroll
  for (int i = 0; i < 8; i++) p[t + 256 * i] = (_Float16)(v[i] * inv);
}

// ---------------------------------------------------------------------------
extern "C" void kernel_launch(void* const* d_in, const int* in_sizes, int n_in,
                              void* d_out, int out_size, void* d_ws, size_t ws_size,
                              hipStream_t stream)
{
  const float* query = (const float*)d_in[0];
  const float* key_  = (const float*)d_in[1];
  const float* value = (const float*)d_in[2];
  const float* Wq = (const float*)d_in[3];
  const float* bq = (const float*)d_in[4];
  const float* Wk = (const float*)d_in[5];
  const float* bk = (const float*)d_in[6];
  const float* Wv = (const float*)d_in[7];
  const float* bv = (const float*)d_in[8];

  char* ws = (char*)d_ws;
  char* ob = (char*)d_out;
  const size_t M64 = (size_t)NB * MAT * 2;   // 64 MiB

  _Float16* q_h  = (_Float16*)(ws);
  _Float16* q_l  = (_Float16*)(ws + M64);
  _Float16* k_h  = q_h;
  _Float16* k_l  = q_l;
  float*    qk   = (float*)(ws);
  _Float16* qT_h = (_Float16*)(ws + 2 * M64);
  _Float16* qT_l = (_Float16*)(ws + 3 * M64);
  _Float16* P    = qT_h;
  _Float16* vT   = qT_l;
  _Float16* kk_h = (_Float16*)(ws + 4 * M64);
  _Float16* kk_l = (_Float16*)(ws + 5 * M64);
  _Float16* val_h = kk_h;

  _Float16* wq_h = (_Float16*)(ob);
  _Float16* wq_l = (_Float16*)(ob + (MAT * 2));
  _Float16* wk_h = (_Float16*)(ob + 2 * (MAT * 2));
  _Float16* wk_l = (_Float16*)(ob + 3 * (MAT * 2));
  _Float16* wv_h = (_Float16*)(ob + 4 * (MAT * 2));
  float* out = (float*)d_out;

  dim3 blk256(256), blk512(512);
  dim3 gg(512);   // 8 batches x 8x8 tiles of 256
  const long NQ8 = (long)NB * MAT / 8;
  const long NW8 = MAT / 8;

  // 1. presplit query (x16), Wq (x16)
  presplit<true><<<dim3(2048), blk256, 0, stream>>>(query, q_h, q_l, NQ8, 16.f);
  presplit<true><<<dim3(2048), blk256, 0, stream>>>(Wq, wq_h, wq_l, NW8, 16.f);
  // 2. qT[e][s] = sum_d Wq[e][d]*query[s][d] + bq[e] (row bias), split out
  gemm4<3, 2, 2><<<gg, blk512, 0, stream>>>(wq_h, wq_l, 0, q_h, q_l, MAT,
                                            bq, 1.f / 256.f, qT_h, qT_l, MAT);
  // 3. presplit key_ (x16), Wk (x16)
  presplit<true><<<dim3(2048), blk256, 0, stream>>>(key_, k_h, k_l, NQ8, 16.f);
  presplit<true><<<dim3(2048), blk256, 0, stream>>>(Wk, wk_h, wk_l, NW8, 16.f);
  // 4. kk[s'][e] = sum_d key_[s'][d]*Wk[e][d] + bk[e] (col bias), split out
  gemm4<3, 1, 2><<<gg, blk512, 0, stream>>>(k_h, k_l, MAT, wk_h, wk_l, 0,
                                            bk, 1.f / 256.f, kk_h, kk_l, MAT);
  // 5. qk[e][s'] = sum_m qT[e][m]*kk[s'][m]  (f32 out)
  gemm4<3, 0, 0><<<gg, blk512, 0, stream>>>(qT_h, qT_l, MAT, kk_h, kk_l, MAT,
                                            nullptr, 1.f / 256.f, qk, nullptr, MAT);
  // 6. P = row-softmax(qk), fp16
  softmax_rows<<<dim3(NB * Sd), blk256, 0, stream>>>(qk, P);
  // 7. presplit value (x1), Wv (x1)
  presplit<false><<<dim3(2048), blk256, 0, stream>>>(value, val_h, nullptr, NQ8, 1.f);
  presplit<false><<<dim3(2048), blk256, 0, stream>>>(Wv, wv_h, nullptr, NW8, 1.f);
  // 8. vT[d'][s'] = sum_d Wv[d'][d]*value[s'][d] + bv[d'] (row bias), fp16
  gemm4<1, 2, 1><<<gg, blk512, 0, stream>>>(wv_h, nullptr, 0, val_h, nullptr, MAT,
                                            bv, 1.f, vT, nullptr, MAT);
  // 9. out[d'][e] = sum_s' vT[d'][s']*P[e][s']  (f32 -> d_out)
  gemm4<1, 0, 0><<<gg, blk512, 0, stream>>>(vT, nullptr, MAT, P, nullptr, MAT,
                                            nullptr, 1.f, out, nullptr, MAT);
}

// Round 5
// 1520.132 us; speedup vs baseline: 1.1268x; 1.1091x over previous
//
#include <hip/hip_runtime.h>
#include <hip/hip_fp16.h>

// Workspace: 384 MiB (same layout as rounds 2-4).
//   A [0,128M):   q_h/l -> k_h/l -> qk (f32)
//   D [128,256M): qT_h/l -> P (64M) + vT (64M)
//   E [256,384M): kk_h/l -> value_h
// d_out scratch (dead before final GEMM): wq_h/l, wk_h/l, wv_h

using half8_t = __attribute__((ext_vector_type(8))) _Float16;
using f32x4   = __attribute__((ext_vector_type(4))) float;

static constexpr int NB = 8;
static constexpr int Sd = 2048;
static constexpr long MAT = (long)Sd * Sd;

__device__ __forceinline__ void gload16(const _Float16* g, _Float16* l) {
  __builtin_amdgcn_global_load_lds(
      (const __attribute__((address_space(1))) void*)g,
      (__attribute__((address_space(3))) void*)l, 16, 0, 0);
}
__device__ __forceinline__ void barrier_() { asm volatile("s_barrier" ::: "memory"); }
#define VMCNT(n) asm volatile("s_waitcnt vmcnt(" #n ")" ::: "memory")
#define SCHEDB() __builtin_amdgcn_sched_barrier(0)

// ---------------------------------------------------------------------------
// presplit: f32 -> fp16 hi (+ residual lo), scaled.
// ---------------------------------------------------------------------------
template<bool SPLIT>
__global__ __launch_bounds__(256) void presplit(const float* __restrict__ in,
    _Float16* __restrict__ h, _Float16* __restrict__ l, long n8, float scl)
{
  long i = (long)blockIdx.x * 256 + threadIdx.x;
  const long stride = (long)gridDim.x * 256;
  for (; i < n8; i += stride) {
    const f32x4* p = (const f32x4*)(in + i * 8);
    f32x4 a = p[0], b = p[1];
    half8_t hh, ll;
#pragma unroll
    for (int j = 0; j < 4; j++) {
      float x = a[j] * scl; _Float16 hv = (_Float16)x;
      hh[j] = hv; if constexpr (SPLIT) ll[j] = (_Float16)(x - (float)hv);
      float y = b[j] * scl; _Float16 hw = (_Float16)y;
      hh[4 + j] = hw; if constexpr (SPLIT) ll[4 + j] = (_Float16)(y - (float)hw);
    }
    *(half8_t*)(h + i * 8) = hh;
    if constexpr (SPLIT) *(half8_t*)(l + i * 8) = ll;
  }
}

// ---------------------------------------------------------------------------
// gemm5 (B^T form): C[i][j] = cscale * sum_k A[i][k]*B[j][k] (+ bias)
// 256x256 tile, phase = K-half unit (256x32, 16KB), ring-of-4 per operand.
// Register frag double-buffer: phase p issues 12 ds_read_b128 for half p+1
// into the alternate frag set + stages half p+3 (4 global_load_lds), then
// 32 MFMA on the current set (compiler-counted lgkmcnt covers the reads
// issued last phase), then vmcnt(4) + ONE barrier (forces stage(p+2),
// published one phase before its reads). 512 threads (8 waves, 2x4).
// NSEG: 1 plain; 3 = K-concat split [Ah|Al|Ah]x[Bh|Bh|Bl] (K=6144).
// BIAS: 0 none, 1 bias[n], 2 bias[m].  OUT: 0 f32, 1 fp16, 2 split fp16(x16).
// ---------------------------------------------------------------------------
template<int NSEG, int BIAS, int OUT>
__global__ __launch_bounds__(512, 2) void gemm5(
    const _Float16* __restrict__ Ah, const _Float16* __restrict__ Al, long sA,
    const _Float16* __restrict__ Bh, const _Float16* __restrict__ Bl, long sB,
    const float* __restrict__ bias, float cscale,
    void* __restrict__ Cp, void* __restrict__ Clp, long sC)
{
  constexpr int NT = NSEG * 32;     // K-tiles
  __shared__ __align__(16) _Float16 LA[4][8192];   // ring of 4 half-units
  __shared__ __align__(16) _Float16 LB[4][8192];

  const int t = threadIdx.x, w = t >> 6, l = t & 63;

  // XCD swizzle: 512 wgs -> 64 consecutive per XCD (one batch per XCD)
  const int wg = blockIdx.x;
  const int swz = (wg & 7) * 64 + (wg >> 3);
  const int bz = swz >> 6, rem = swz & 63;
  const int by = rem >> 3, bx = rem & 7;

  const _Float16* PAh = Ah + (size_t)bz * sA + (size_t)(by * 256) * Sd;
  const _Float16* PBh = Bh + (size_t)bz * sB + (size_t)(bx * 256) * Sd;
  const _Float16* PAl = (NSEG == 3) ? Al + (size_t)bz * sA + (size_t)(by * 256) * Sd : PAh;
  const _Float16* PBl = (NSEG == 3) ? Bl + (size_t)bz * sB + (size_t)(bx * 256) * Sd : PBh;

  // staging geometry: slot S = i*512 + t -> row 2*(S>>3)+(S&1),
  // k-slot lk = ((S&7)>>1) ^ ((S>>3)&3); dest LDS = linear slot*8.
  const int s7 = t & 7;
  const int lkS = (s7 >> 1) ^ ((t >> 3) & 3);
  const size_t srcoff = (size_t)(2 * (t >> 3) + (s7 & 1)) * Sd + lkS * 8;
  const int du0 = w * 512;

  // read geometry (inverse involution; measured conflict-free)
  const int wm = (w >> 2) * 128, wn = (w & 3) * 64;
  const int lm = l & 15, lkr = l >> 4;
  const int sprime = ((lkr ^ ((lm >> 1) & 3)) << 1) | (lm & 1);
  const int aoff = (wm >> 1) * 128 + (lm >> 1) * 128 + sprime * 16;
  const int boff = (wn >> 1) * 128 + (lm >> 1) * 128 + sprime * 16;

  // half hp -> source pointers / k offset
  auto srcA = [&](int hp) -> const _Float16* {
    if constexpr (NSEG == 3) return ((hp >> 6) == 1) ? PAl : PAh;
    return PAh;
  };
  auto srcB = [&](int hp) -> const _Float16* {
    if constexpr (NSEG == 3) return ((hp >> 6) == 2) ? PBl : PBh;
    return PBh;
  };
  auto koOf = [&](int hp) -> int {
    if constexpr (NSEG == 3) return (hp & 63) * 32;
    return hp * 32;
  };
  auto stageH = [&](int hp) {   // 4 global_load_lds
    const int u = hp & 3;
    const _Float16* a = srcA(hp) + koOf(hp);
    const _Float16* b = srcB(hp) + koOf(hp);
    gload16(a + srcoff, LA[u] + du0);
    gload16(a + srcoff + (size_t)128 * Sd, LA[u] + du0 + 4096);
    gload16(b + srcoff, LB[u] + du0);
    gload16(b + srcoff + (size_t)128 * Sd, LB[u] + du0 + 4096);
  };

  f32x4 acc[8][4] = {};
  half8_t fA0[8], fB0[4], fA1[8], fB1[4];

  auto readF = [&](int u, half8_t (&fa)[8], half8_t (&fb)[4]) {  // 12 b128
#pragma unroll
    for (int f = 0; f < 8; f++)
      fa[f] = *(const half8_t*)((const char*)LA[u] + aoff + f * 1024);
#pragma unroll
    for (int n = 0; n < 4; n++)
      fb[n] = *(const half8_t*)((const char*)LB[u] + boff + n * 1024);
  };
  auto mfma32 = [&](const half8_t (&fa)[8], const half8_t (&fb)[4]) {
    __builtin_amdgcn_s_setprio(1);
#pragma unroll
    for (int f = 0; f < 8; f++)
#pragma unroll
      for (int n = 0; n < 4; n++)
        acc[f][n] = __builtin_amdgcn_mfma_f32_16x16x32_f16(fa[f], fb[n], acc[f][n], 0, 0, 0);
    __builtin_amdgcn_s_setprio(0);
  };

  // ---- prologue: stage halves 0,1,2; force 0,1; read half-0 frags
  stageH(0); stageH(1); stageH(2);
  VMCNT(4);            // 12 outstanding -> forces stage(0), stage(1)
  barrier_();
  readF(0, fA0, fB0);

  // ---- main loop: tiles j=0..NT-2 (two phases each), tile NT-1 peeled
  for (int j = 0; j < NT - 1; ++j) {
    const int p0 = 2 * j;
    // even phase p0: consume half p0, read half p0+1, stage half p0+3
    readF((p0 + 1) & 3, fA1, fB1);
    stageH(p0 + 3);
    SCHEDB();
    mfma32(fA0, fB0);
    VMCNT(4);          // forces stage(p0+2)
    barrier_();
    // odd phase p0+1: consume half p0+1, read half p0+2, stage half p0+4
    readF((p0 + 2) & 3, fA0, fB0);
    if (j < NT - 2) stageH(p0 + 4);
    SCHEDB();
    mfma32(fA1, fB1);
    if (j == NT - 2) { VMCNT(0); } else { VMCNT(4); }   // forces stage(p0+3)
    barrier_();
  }
  // ---- peeled last tile (j = NT-1): halves 2NT-2, 2NT-1
  {
    const int p0 = 2 * (NT - 1);
    readF((p0 + 1) & 3, fA1, fB1);
    SCHEDB();
    mfma32(fA0, fB0);
    SCHEDB();
    mfma32(fA1, fB1);
  }

  // ---- epilogue: C/D layout col = lane&15, row = (lane>>4)*4 + reg
  const int row_base = by * 256 + wm + (lkr << 2);
  const int col_base = bx * 256 + wn + lm;
#pragma unroll
  for (int fm = 0; fm < 8; fm++)
#pragma unroll
    for (int fn = 0; fn < 4; fn++) {
      const int n = col_base + fn * 16;
      float bcol = 0.f;
      if constexpr (BIAS == 1) bcol = bias[n];
#pragma unroll
      for (int r = 0; r < 4; r++) {
        const int m = row_base + fm * 16 + r;
        float v = acc[fm][fn][r] * cscale;
        if constexpr (BIAS == 1) v += bcol;
        if constexpr (BIAS == 2) v += bias[m];
        const size_t ci = (size_t)bz * sC + (size_t)m * Sd + n;
        if constexpr (OUT == 0) ((float*)Cp)[ci] = v;
        else if constexpr (OUT == 1) ((_Float16*)Cp)[ci] = (_Float16)v;
        else {
          float sv = v * 16.0f;
          _Float16 hv = (_Float16)sv;
          ((_Float16*)Cp)[ci]  = hv;
          ((_Float16*)Clp)[ci] = (_Float16)(sv - (float)hv);
        }
      }
    }
}

// ---------------------------------------------------------------------------
// Row softmax: one 256-thread block per row of 2048 f32 -> fp16 probs.
// ---------------------------------------------------------------------------
__global__ __launch_bounds__(256) void softmax_rows(const float* __restrict__ X,
                                                    _Float16* __restrict__ P)
{
  __shared__ float red[4];
  const size_t row = blockIdx.x;
  const float* x = X + row * Sd;
  _Float16* p = P + row * Sd;
  const int t = threadIdx.x;
  float v[8];
  float mx = -1e30f;
#pragma unroll
  for (int i = 0; i < 8; i++) { v[i] = x[t + 256 * i]; mx = fmaxf(mx, v[i]); }
#pragma unroll
  for (int o = 32; o > 0; o >>= 1) mx = fmaxf(mx, __shfl_xor(mx, o, 64));
  if ((t & 63) == 0) red[t >> 6] = mx;
  __syncthreads();
  mx = fmaxf(fmaxf(red[0], red[1]), fmaxf(red[2], red[3]));
  __syncthreads();
  float s = 0.f;
#pragma unroll
  for (int i = 0; i < 8; i++) { v[i] = __expf(v[i] - mx); s += v[i]; }
#pragma unroll
  for (int o = 32; o > 0; o >>= 1) s += __shfl_xor(s, o, 64);
  if ((t & 63) == 0) red[t >> 6] = s;
  __syncthreads();
  s = red[0] + red[1] + red[2] + red[3];
  float inv = 1.f / s;
#pragma unroll
  for (int i = 0; i < 8; i++) p[t + 256 * i] = (_Float16)(v[i] * inv);
}

// ---------------------------------------------------------------------------
extern "C" void kernel_launch(void* const* d_in, const int* in_sizes, int n_in,
                              void* d_out, int out_size, void* d_ws, size_t ws_size,
                              hipStream_t stream)
{
  const float* query = (const float*)d_in[0];
  const float* key_  = (const float*)d_in[1];
  const float* value = (const float*)d_in[2];
  const float* Wq = (const float*)d_in[3];
  const float* bq = (const float*)d_in[4];
  const float* Wk = (const float*)d_in[5];
  const float* bk = (const float*)d_in[6];
  const float* Wv = (const float*)d_in[7];
  const float* bv = (const float*)d_in[8];

  char* ws = (char*)d_ws;
  char* ob = (char*)d_out;
  const size_t M64 = (size_t)NB * MAT * 2;   // 64 MiB

  _Float16* q_h  = (_Float16*)(ws);
  _Float16* q_l  = (_Float16*)(ws + M64);
  _Float16* k_h  = q_h;
  _Float16* k_l  = q_l;
  float*    qk   = (float*)(ws);
  _Float16* qT_h = (_Float16*)(ws + 2 * M64);
  _Float16* qT_l = (_Float16*)(ws + 3 * M64);
  _Float16* P    = qT_h;
  _Float16* vT   = qT_l;
  _Float16* kk_h = (_Float16*)(ws + 4 * M64);
  _Float16* kk_l = (_Float16*)(ws + 5 * M64);
  _Float16* val_h = kk_h;

  _Float16* wq_h = (_Float16*)(ob);
  _Float16* wq_l = (_Float16*)(ob + (MAT * 2));
  _Float16* wk_h = (_Float16*)(ob + 2 * (MAT * 2));
  _Float16* wk_l = (_Float16*)(ob + 3 * (MAT * 2));
  _Float16* wv_h = (_Float16*)(ob + 4 * (MAT * 2));
  float* out = (float*)d_out;

  dim3 blk256(256), blk512(512);
  dim3 gg(512);   // 8 batches x 8x8 tiles of 256
  const long NQ8 = (long)NB * MAT / 8;
  const long NW8 = MAT / 8;

  // 1. presplit query (x16), Wq (x16)
  presplit<true><<<dim3(2048), blk256, 0, stream>>>(query, q_h, q_l, NQ8, 16.f);
  presplit<true><<<dim3(2048), blk256, 0, stream>>>(Wq, wq_h, wq_l, NW8, 16.f);
  // 2. qT[e][s] = sum_d Wq[e][d]*query[s][d] + bq[e] (row bias), split out
  gemm5<3, 2, 2><<<gg, blk512, 0, stream>>>(wq_h, wq_l, 0, q_h, q_l, MAT,
                                            bq, 1.f / 256.f, qT_h, qT_l, MAT);
  // 3. presplit key_ (x16), Wk (x16)
  presplit<true><<<dim3(2048), blk256, 0, stream>>>(key_, k_h, k_l, NQ8, 16.f);
  presplit<true><<<dim3(2048), blk256, 0, stream>>>(Wk, wk_h, wk_l, NW8, 16.f);
  // 4. kk[s'][e] = sum_d key_[s'][d]*Wk[e][d] + bk[e] (col bias), split out
  gemm5<3, 1, 2><<<gg, blk512, 0, stream>>>(k_h, k_l, MAT, wk_h, wk_l, 0,
                                            bk, 1.f / 256.f, kk_h, kk_l, MAT);
  // 5. qk[e][s'] = sum_m qT[e][m]*kk[s'][m]  (f32 out)
  gemm5<3, 0, 0><<<gg, blk512, 0, stream>>>(qT_h, qT_l, MAT, kk_h, kk_l, MAT,
                                            nullptr, 1.f / 256.f, qk, nullptr, MAT);
  // 6. P = row-softmax(qk), fp16
  softmax_rows<<<dim3(NB * Sd), blk256, 0, stream>>>(qk, P);
  // 7. presplit value (x1), Wv (x1)
  presplit<false><<<dim3(2048), blk256, 0, stream>>>(value, val_h, nullptr, NQ8, 1.f);
  presplit<false><<<dim3(2048), blk256, 0, stream>>>(Wv, wv_h, nullptr, NW8, 1.f);
  // 8. vT[d'][s'] = sum_d Wv[d'][d]*value[s'][d] + bv[d'] (row bias), fp16
  gemm5<1, 2, 1><<<gg, blk512, 0, stream>>>(wv_h, nullptr, 0, val_h, nullptr, MAT,
                                            bv, 1.f, vT, nullptr, MAT);
  // 9. out[d'][e] = sum_s' vT[d'][s']*P[e][s']  (f32 -> d_out)
  gemm5<1, 0, 0><<<gg, blk512, 0, stream>>>(vT, nullptr, MAT, P, nullptr, MAT,
                                            nullptr, 1.f, out, nullptr, MAT);
}